// Round 12
// baseline (449.530 us; speedup 1.0000x reference)
//
#include <hip/hip_runtime.h>
#include <hip/hip_bf16.h>
#include <hip/hip_cooperative_groups.h>
#include <cstdint>
#include <math.h>

namespace cg = cooperative_groups;

// Problem constants
#define T_  4
#define B_  32
#define C_  384
#define HF_ 1536
#define HW_ 196
#define E_  8
#define N_  128
#define NROW 1792          // (n,h) units
#define NGT  50176
#define LCAP 64

#define LIFW (B_ * C_ / 4)    // 3072 lif units (4 waves each, wave per (b,c) row)
#define TRB  (E_ * 12 * 24)   // 2304 transpose tiles
#define PRB  48
#define COMBB ((N_ * C_ * 49) / 256)   // 9408 combine units

struct FP {
  const float *x, *rw, *rbv, *rg, *rbeta, *rmean, *rvar, *w1;
  const float *b1, *g1, *be1, *m1, *v1;
  const float *w2, *b2, *g2, *be2, *m2, *v2, *taus;
  float *out, *aux;
  int *header;              // [1] = qcount
  float *f_acc, *p_acc;
  float *cnt;
  int *sel_e; float *sel_g, *gsum, *K;
  float *A, *Bc, *const2, *inv2v;
  __hip_bfloat16 *w1t;
  int *queue;
  unsigned short *list16;
  float *rowmaxp, *rowmax, *thrmin;
  unsigned char *levels;
};

// ---------------------------------------------------------------------------
// Single cooperative kernel: P1 lifprep | P2 router | P3 lists+combine |
// P4 gather — R6's proven bodies, grid-stride phases, grid.sync barriers.
// ---------------------------------------------------------------------------
__global__ __launch_bounds__(256, 4) void k_fused(FP p) {
  __shared__ __align__(16) char smraw[8448];   // union: tile / sc / xs8
  __shared__ int s_i1, s_i2;
  __shared__ float s_g1, s_g2;
  cg::grid_group grid = cg::this_grid();
  int tid = threadIdx.x;
  int gsz = gridDim.x;

  // ===================== P1: LIF+levels, transpose, prep =====================
  for (int blk = blockIdx.x; blk < LIFW + TRB + PRB; blk += gsz) {
    if (blk < LIFW) {
      int lane = tid & 63, wave = tid >> 6;
      int bc = blk * 4 + wave;
      bool act = lane < 49;                   // 49 float4 = 196 positions
      float te[E_];
      #pragma unroll
      for (int e2 = 0; e2 < E_; ++e2) {
        float t = p.taus[e2];
        float y = t;                          // y/t == 1.0 -> satisfies
        #pragma unroll
        for (int it = 0; it < 4; ++it) {
          float cnd = __uint_as_float(__float_as_uint(y) - 1u);
          if (cnd / t - 1.0f >= 0.0f) y = cnd; else break;
        }
        te[e2] = y;
      }
      const float4* xr = (const float4*)p.x;
      unsigned int* levels4 = (unsigned int*)p.levels;
      size_t rowb = (size_t)bc * 49 + (act ? lane : 0);
      const size_t ts4 = (size_t)B_ * C_ * 49;
      float4 v = {0.f, 0.f, 0.f, 0.f};
      unsigned int counts = 0;
      unsigned int pk[T_];
      #pragma unroll
      for (int t = 0; t < T_; ++t) {
        float4 xv;
        if (act) xv = xr[rowb + (size_t)t * ts4];
        else { xv.x = xv.y = xv.z = xv.w = -1e30f; }
        int l0 = 0, l1 = 0, l2 = 0, l3 = 0;
        #pragma unroll
        for (int e2 = 0; e2 < E_; ++e2) {
          l0 += (xv.x >= te[e2]) ? 1 : 0;
          l1 += (xv.y >= te[e2]) ? 1 : 0;
          l2 += (xv.z >= te[e2]) ? 1 : 0;
          l3 += (xv.w >= te[e2]) ? 1 : 0;
        }
        pk[t] = (unsigned int)l0 | ((unsigned int)l1 << 8) |
                ((unsigned int)l2 << 16) | ((unsigned int)l3 << 24);
        v.x = v.x + (xv.x - v.x) * 0.5f;      // tau=2.0
        v.y = v.y + (xv.y - v.y) * 0.5f;
        v.z = v.z + (xv.z - v.z) * 0.5f;
        v.w = v.w + (xv.w - v.w) * 0.5f;
        int cl = 0;
        if (v.x - 1.0f >= 0.0f) { v.x = 0.f; ++cl; }
        if (v.y - 1.0f >= 0.0f) { v.y = 0.f; ++cl; }
        if (v.z - 1.0f >= 0.0f) { v.z = 0.f; ++cl; }
        if (v.w - 1.0f >= 0.0f) { v.w = 0.f; ++cl; }
        counts += (unsigned int)cl << (8 * t);
      }
      if (act) {
        #pragma unroll
        for (int t = 0; t < T_; ++t)
          levels4[rowb + (size_t)t * ts4] = pk[t];
      }
      #pragma unroll
      for (int off = 1; off < 64; off <<= 1)
        counts += (unsigned int)__shfl_xor((int)counts, off, 64);
      if (lane == 0) {
        #pragma unroll
        for (int t = 0; t < T_; ++t)
          p.cnt[(size_t)t * B_ * C_ + bc] = (float)((counts >> (8 * t)) & 0xffu);
      }
    } else if (blk < LIFW + TRB) {
      float (*tile)[33] = (float(*)[33])smraw;
      __syncthreads();                        // protect tile across iterations
      int rem = blk - LIFW;
      int e = rem / 288, r2 = rem % 288;
      int ct = r2 / 24, ot = r2 % 24;
      int c0 = ct * 32, o0 = ot * 64;
      int cl = tid & 31, olb = tid >> 5;
      #pragma unroll
      for (int it = 0; it < 8; ++it) {
        int ol = olb + it * 8;
        tile[ol][cl] = p.w1[(size_t)(e * HF_ + o0 + ol) * C_ + c0 + cl];
      }
      __syncthreads();
      int ol2 = tid & 63, clb = tid >> 6;
      #pragma unroll
      for (int it = 0; it < 8; ++it) {
        int cl2 = clb + it * 4;
        p.w1t[(size_t)(e * C_ + c0 + cl2) * HF_ + o0 + ol2] =
            __float2bfloat16(tile[ol2][cl2]);
      }
      if (tid < 32) {
        float m = 0.f;
        for (int ol = 0; ol < 64; ++ol) {
          float bv = __bfloat162float(__float2bfloat16(tile[ol][tid]));
          m = fmaxf(m, fabsf(bv));
        }
        p.rowmaxp[(size_t)(e * C_ + c0 + tid) * 24 + ot] = m;
      }
    } else {
      int idx = (blk - LIFW - TRB) * 256 + tid;
      if (idx < 64) p.header[idx] = 0;
      if (idx < E_ * HF_) {
        int e = idx / HF_;
        float inv = p.g1[idx] / sqrtf(p.v1[idx] + 1e-5f);
        float sh  = p.be1[idx] - p.m1[idx] * inv;
        p.A[idx]  = inv;
        p.Bc[idx] = inv * p.b1[idx] + sh - p.taus[e];
      }
      if (idx < E_ * C_) {
        float inv = p.g2[idx] / sqrtf(p.v2[idx] + 1e-5f);
        p.const2[idx] = p.b2[idx] * inv + (p.be2[idx] - p.m2[idx] * inv);
        p.inv2v[idx]  = inv;
      }
    }
  }
  grid.sync();

  // ===================== P2: router + rowmax + thrmin =====================
  for (int bid = blockIdx.x; bid < N_ + 13; bid += gsz) {
    float* sc = (float*)smraw;                // C_+256+E_ floats = 2592 B
    if (bid < N_) {
      int n = bid;
      float* part = sc + C_;
      float* lg = part + 256;
      for (int c = tid; c < C_; c += 256) sc[c] = p.cnt[(size_t)n * C_ + c];
      __syncthreads();
      {
        int e = tid >> 5, sub = tid & 31;
        float d = 0.f;
        for (int c = sub; c < C_; c += 32) d += p.rw[e * C_ + c] * sc[c];
        part[tid] = d;
      }
      __syncthreads();
      if (tid < E_) {
        float dot = 0.f;
        #pragma unroll
        for (int j = 0; j < 32; ++j) dot += part[tid * 32 + j];
        float inv = p.rg[tid] / sqrtf(p.rvar[tid] + 1e-5f);
        lg[tid] = (dot * (1.0f / HW_) + p.rbv[tid]) * inv +
                  (p.rbeta[tid] - p.rmean[tid] * inv);
      }
      __syncthreads();
      if (tid == 0) {
        float m = lg[0];
        for (int e = 1; e < E_; ++e) m = fmaxf(m, lg[e]);
        float pr[E_]; float s = 0.f;
        for (int e = 0; e < E_; ++e) { pr[e] = expf(lg[e] - m); s += pr[e]; }
        float invs = 1.0f / s;
        for (int e = 0; e < E_; ++e) pr[e] *= invs;
        int i1 = 0;
        for (int e = 1; e < E_; ++e) if (pr[e] > pr[i1]) i1 = e;
        int i2 = (i1 == 0) ? 1 : 0;
        for (int e = 0; e < E_; ++e) if (e != i1 && pr[e] > pr[i2]) i2 = e;
        float w = pr[i1] + pr[i2];
        float ga = pr[i1] / w, gb = pr[i2] / w;
        p.sel_e[2 * n] = i1; p.sel_e[2 * n + 1] = i2;
        p.sel_g[2 * n] = ga; p.sel_g[2 * n + 1] = gb;
        p.gsum[n] = ga + gb;
        s_i1 = i1; s_i2 = i2; s_g1 = ga; s_g2 = gb;
        atomicAdd(&p.f_acc[i1], 1.0f);
        atomicAdd(&p.f_acc[i2], 1.0f);
        for (int e = 0; e < E_; ++e) atomicAdd(&p.p_acc[e], pr[e]);
      }
      __syncthreads();
      int i1 = s_i1, i2 = s_i2; float ga = s_g1, gb = s_g2;
      for (int c = tid; c < C_; c += 256)
        p.K[(size_t)n * C_ + c] =
            ga * p.const2[i1 * C_ + c] + gb * p.const2[i2 * C_ + c];
    } else if (bid < N_ + 12) {
      int idx = (bid - N_) * 256 + tid;
      if (idx < E_ * C_) {
        float m = 0.f;
        #pragma unroll
        for (int t = 0; t < 24; ++t)
          m = fmaxf(m, p.rowmaxp[(size_t)idx * 24 + t]);
        p.rowmax[idx] = m;
      }
    } else {
      float* red = sc;
      for (int e = 0; e < E_; ++e) {
        float m = INFINITY;
        for (int o = tid; o < HF_; o += 256) {
          float a = p.A[e * HF_ + o], b = p.Bc[e * HF_ + o];
          float thr = (a != 0.0f) ? (-b / fabsf(a))
                                  : ((b >= 0.0f) ? -INFINITY : INFINITY);
          m = fminf(m, thr);
        }
        red[tid] = m;
        __syncthreads();
        for (int s = 128; s > 0; s >>= 1) {
          if (tid < s) red[tid] = fminf(red[tid], red[tid + s]);
          __syncthreads();
        }
        if (tid == 0) p.thrmin[e] = red[0];
        __syncthreads();
      }
    }
  }
  grid.sync();

  // ===================== P3: lists + combine =====================
  for (int bid = blockIdx.x; bid < NROW + COMBB; bid += gsz) {
    if (bid >= NROW) {
      int idx = (bid - NROW) * 256 + tid;     // over N*C*49 float4s
      int nc = idx / 49;
      float g = p.gsum[nc / C_];
      float kc = p.K[nc];
      float4 v = ((const float4*)p.x)[idx];
      v.x = g * v.x + kc;
      v.y = g * v.y + kc;
      v.z = g * v.z + kc;
      v.w = g * v.w + kc;
      ((float4*)p.out)[idx] = v;
    } else {
      unsigned char* xs8 = (unsigned char*)smraw;   // [w][c], 5376 B
      __syncthreads();                              // protect across iterations
      int lane = tid & 63, wave = tid >> 6;
      int n = bid / 14, h = bid - n * 14;
      unsigned long long lmask = (1ull << lane) - 1ull;

      if (bid == 0 && tid == 0) {
        float s = 0.f;
        for (int e = 0; e < E_; ++e)
          s += (p.f_acc[e] * (1.0f / N_)) * (p.p_acc[e] * (1.0f / N_));
        *p.aux = 0.01f * E_ * s;
      }

      for (int c = tid; c < C_; c += 256) {
        const unsigned short* pp =
            (const unsigned short*)(p.levels + (size_t)(n * C_ + c) * HW_ + h * 14);
        #pragma unroll
        for (int i = 0; i < 7; ++i) {
          unsigned short u = pp[i];
          xs8[(2 * i) * C_ + c]     = (unsigned char)(u & 0xff);
          xs8[(2 * i + 1) * C_ + c] = (unsigned char)(u >> 8);
        }
      }
      __syncthreads();

      for (int t = wave; t < 28; t += 4) {
        int k = t / 14, w = t - k * 14;
        int pair = 2 * n + k;
        int e = p.sel_e[pair];
        const float* rme = p.rowmax + e * C_;
        unsigned long long masks[6];
        int nnz = 0;
        float myb = 0.f;
        #pragma unroll
        for (int cb = 0; cb < 6; ++cb) {
          int c = cb * 64 + lane;
          bool sp = ((int)xs8[w * C_ + c] > e);   // level > e <=> spike
          unsigned long long m = __ballot(sp);
          masks[cb] = m;
          if (sp) myb += rme[c];
          nnz += __popcll(m);
        }
        #pragma unroll
        for (int off = 1; off < 64; off <<= 1) myb += __shfl_xor(myb, off, 64);
        bool prune = (myb < p.thrmin[e] - 1e-4f);
        if (!prune) {
          int tw = pair * 196 + h * 14 + w;
          size_t lbase = (size_t)tw * LCAP;
          int cum = 0;
          #pragma unroll
          for (int cb = 0; cb < 6; ++cb) {
            unsigned long long m = masks[cb];
            bool sp = (m >> lane) & 1ull;
            int pos = cum + __popcll(m & lmask);
            if (sp && pos < LCAP)
              p.list16[lbase + pos] = (unsigned short)(cb * 64 + lane);
            cum += __popcll(m);
          }
          if (lane == 0) {
            int nv = nnz < LCAP ? nnz : LCAP;
            int qi = atomicAdd(&p.header[1], 1);
            p.queue[qi] = tw | (nv << 20);
          }
        }
      }
    }
  }
  grid.sync();

  // ===================== P4: gather =====================
  {
    int nq = p.header[1];
    int wid = blockIdx.x * 4 + (tid >> 6);
    int lane = tid & 63;
    int nwaves = gsz * 4;

    for (int qi = wid; qi < nq; qi += nwaves) {
      int ent = p.queue[qi];
      int tw = ent & 0xFFFFF;
      int nnz = ent >> 20;
      int pair = tw / HW_, pos = tw - pair * HW_;
      int n = pair >> 1;
      int e = p.sel_e[pair];
      int lv = (int)p.list16[(size_t)tw * LCAP + lane];
      const uint4* wb = (const uint4*)(p.w1t + (size_t)e * C_ * HF_);

      #pragma unroll
      for (int pass = 0; pass < 3; ++pass) {
        const uint4* wbp = wb + pass * 64 + lane;
        float acc[8];
        #pragma unroll
        for (int q = 0; q < 8; ++q) acc[q] = 0.f;
        int j = 0;
        for (; j + 4 <= nnz; j += 4) {
          int c0 = __shfl(lv, j + 0);
          int c1 = __shfl(lv, j + 1);
          int c2 = __shfl(lv, j + 2);
          int c3 = __shfl(lv, j + 3);
          uint4 a = wbp[c0 * 192];
          uint4 b = wbp[c1 * 192];
          uint4 c = wbp[c2 * 192];
          uint4 d = wbp[c3 * 192];
          uint32_t ua[4] = {a.x, a.y, a.z, a.w};
          uint32_t ub[4] = {b.x, b.y, b.z, b.w};
          uint32_t uc[4] = {c.x, c.y, c.z, c.w};
          uint32_t ud[4] = {d.x, d.y, d.z, d.w};
          #pragma unroll
          for (int q = 0; q < 4; ++q) {
            acc[2 * q]     += __uint_as_float(ua[q] << 16) + __uint_as_float(ub[q] << 16) +
                              __uint_as_float(uc[q] << 16) + __uint_as_float(ud[q] << 16);
            acc[2 * q + 1] += __uint_as_float(ua[q] & 0xffff0000u) + __uint_as_float(ub[q] & 0xffff0000u) +
                              __uint_as_float(uc[q] & 0xffff0000u) + __uint_as_float(ud[q] & 0xffff0000u);
          }
        }
        for (; j < nnz; ++j) {
          int c0 = __shfl(lv, j);
          uint4 a = wbp[c0 * 192];
          uint32_t ua[4] = {a.x, a.y, a.z, a.w};
          #pragma unroll
          for (int q = 0; q < 4; ++q) {
            acc[2 * q]     += __uint_as_float(ua[q] << 16);
            acc[2 * q + 1] += __uint_as_float(ua[q] & 0xffff0000u);
          }
        }
        int k2 = (pass * 64 + lane) * 2;
        float4 Av0 = ((const float4*)(p.A + e * HF_))[k2];
        float4 Av1 = ((const float4*)(p.A + e * HF_))[k2 + 1];
        float4 Bv0 = ((const float4*)(p.Bc + e * HF_))[k2];
        float4 Bv1 = ((const float4*)(p.Bc + e * HF_))[k2 + 1];
        float av[8] = {Av0.x, Av0.y, Av0.z, Av0.w, Av1.x, Av1.y, Av1.z, Av1.w};
        float bv[8] = {Bv0.x, Bv0.y, Bv0.z, Bv0.w, Bv1.x, Bv1.y, Bv1.z, Bv1.w};
        #pragma unroll
        for (int q = 0; q < 8; ++q) {
          unsigned long long fm = __ballot(av[q] * acc[q] + bv[q] >= 0.0f);
          while (fm) {                         // rare layer-2 spikes
            int b = __ffsll(fm) - 1;
            fm &= fm - 1;
            int o = (pass * 64 + b) * 8 + q;
            float gk = p.sel_g[pair];
            const float* w2r = p.w2 + (size_t)e * C_ * HF_ + o;
            const float* ivr = p.inv2v + e * C_;
            for (int c = lane; c < C_; c += 64) {
              atomicAdd(&p.out[((size_t)(n * C_ + c)) * HW_ + pos],
                        gk * ivr[c] * w2r[(size_t)c * HF_]);
            }
          }
        }
      }
    }
  }
}

// ---------------------------------------------------------------------------
// Launch: single cooperative dispatch
// ---------------------------------------------------------------------------
extern "C" void kernel_launch(void* const* d_in, const int* in_sizes, int n_in,
                              void* d_out, int out_size, void* d_ws, size_t ws_size,
                              hipStream_t stream) {
  char* ws = (char*)d_ws;
  FP p;
  p.x      = (const float*)d_in[0];
  p.rw     = (const float*)d_in[1];
  p.rbv    = (const float*)d_in[2];
  p.rg     = (const float*)d_in[3];
  p.rbeta  = (const float*)d_in[4];
  p.rmean  = (const float*)d_in[5];
  p.rvar   = (const float*)d_in[6];
  p.w1     = (const float*)d_in[7];
  p.b1     = (const float*)d_in[8];
  p.g1     = (const float*)d_in[9];
  p.be1    = (const float*)d_in[10];
  p.m1     = (const float*)d_in[11];
  p.v1     = (const float*)d_in[12];
  p.w2     = (const float*)d_in[13];
  p.b2     = (const float*)d_in[14];
  p.g2     = (const float*)d_in[15];
  p.be2    = (const float*)d_in[16];
  p.m2     = (const float*)d_in[17];
  p.v2     = (const float*)d_in[18];
  p.taus   = (const float*)d_in[19];
  p.out    = (float*)d_out;
  p.aux    = (float*)d_out + (out_size - 1);
  p.header = (int*)ws;
  p.f_acc  = (float*)ws + 8;
  p.p_acc  = (float*)ws + 16;
  p.cnt    = (float*)(ws + 256);
  p.sel_e  = (int*)(ws + 196864);
  p.sel_g  = (float*)(ws + 197888);
  p.gsum   = (float*)(ws + 198912);
  p.K      = (float*)(ws + 199424);
  p.A      = (float*)(ws + 396032);
  p.Bc     = (float*)(ws + 445184);
  p.const2 = (float*)(ws + 494336);
  p.inv2v  = (float*)(ws + 506624);
  p.w1t    = (__hip_bfloat16*)(ws + 715520);
  p.queue  = (int*)(ws + 10152704);
  p.list16 = (unsigned short*)(ws + 10353408);
  p.rowmaxp= (float*)(ws + 16775936);
  p.rowmax = (float*)(ws + 17070848);
  p.thrmin = (float*)(ws + 17083136);
  p.levels = (unsigned char*)(ws + 17084416);

  static int s_grid = 0;
  if (s_grid == 0) {
    int nb = 0;
    hipOccupancyMaxActiveBlocksPerMultiprocessor(&nb, (const void*)k_fused, 256, 0);
    if (nb < 1) nb = 1;
    int dev = 0;
    hipGetDevice(&dev);
    hipDeviceProp_t prop;
    hipGetDeviceProperties(&prop, dev);
    int g = nb * prop.multiProcessorCount;
    if (g > 1024) g = 1024;
    if (g < 256) g = 256;
    s_grid = g;
  }

  void* args[] = {&p};
  hipLaunchCooperativeKernel((const void*)k_fused, dim3(s_grid), dim3(256),
                             args, 0, stream);
}